// Round 4
// baseline (129.421 us; speedup 1.0000x reference)
//
#include <hip/hip_runtime.h>
#include <hip/hip_bf16.h>

typedef float f4 __attribute__((ext_vector_type(4)));
typedef unsigned short us8 __attribute__((ext_vector_type(8)));
typedef short bfrag __attribute__((ext_vector_type(8)));     // 8 bf16
typedef float f16v __attribute__((ext_vector_type(16)));

constexpr int NN   = 4096;
constexpr int FINc = 512;
constexpr int FOUTc= 128;
constexpr int KHc  = 4;
constexpr int KFc  = 512;
constexpr float ALPHA = 0.2f;
constexpr float LOG2E = 1.44269504088896340736f;

static __device__ __forceinline__ unsigned short f2bf(float f) {
    unsigned u = __float_as_uint(f);
    return (unsigned short)((u + 0x7fffu + ((u >> 16) & 1u)) >> 16);   // RNE
}
static __device__ __forceinline__ float bf2f(unsigned short u) {
    return __uint_as_float(((unsigned)u) << 16);
}

// ---------------- kernel 0: adj -> bitmask ----------------
__global__ __launch_bounds__(256) void bits_kernel(const int* __restrict__ adj,
                                                   unsigned* __restrict__ bits) {
    size_t idx = (size_t)blockIdx.x * 256 + threadIdx.x;
    unsigned long long b = __ballot(adj[idx] != 0);
    int l = threadIdx.x & 63;
    if (l == 0)       bits[idx >> 5] = (unsigned)b;
    else if (l == 32) bits[idx >> 5] = (unsigned)(b >> 32);
}

// ---------------- kernel 1: cast x -> xb (bf16), W -> WbT[k][o][f] (bf16) ----------------
__global__ __launch_bounds__(256) void prep_kernel(const float* __restrict__ x,
                                                   const float* __restrict__ W,
                                                   unsigned short* __restrict__ xb,
                                                   unsigned short* __restrict__ WbT) {
    const int b = blockIdx.x, t = threadIdx.x;
    if (b < 1024) {                       // x: 2M elements, 8 per thread
        size_t base = ((size_t)b * 256 + t) * 8;
        f4 v0 = *(const f4*)&x[base];
        f4 v1 = *(const f4*)&x[base + 4];
        us8 o;
#pragma unroll
        for (int j = 0; j < 4; ++j) { o[j] = f2bf(v0[j]); o[4 + j] = f2bf(v1[j]); }
        *(us8*)&xb[base] = o;
    } else {                              // W transpose: 512 threads, one per (k,o)
        int idx = (b - 1024) * 256 + t;
        int k = idx >> 7, o = idx & 127;
        const float* src = &W[(size_t)k * 65536 + o];        // stride 128 over f
        unsigned short* dst = &WbT[((size_t)k * 128 + o) * FINc];
        for (int f8 = 0; f8 < FINc; f8 += 8) {
            us8 v;
#pragma unroll
            for (int j = 0; j < 8; ++j) v[j] = f2bf(src[(size_t)(f8 + j) * 128]);
            *(us8*)&dst[f8] = v;
        }
    }
}

// ---------------- kernel 2: hT[k][o][m] = (x @ W) bf16 via MFMA ----------------
__global__ __launch_bounds__(256) void gemmh_kernel(const unsigned short* __restrict__ xb,
                                                    const unsigned short* __restrict__ WbT,
                                                    unsigned short* __restrict__ hT) {
    __shared__ char Ax[64 * 128];
    __shared__ char Bx[64 * 128];
    const int t = threadIdx.x, wid = t >> 6, lane = t & 63;
    const int c0 = blockIdx.x * 64, n0 = blockIdx.y * 64;
    const int head = c0 >> 7, ob = c0 & 127;
    const int srow = t >> 2, sseg = t & 3;
    const unsigned short* asrc = &xb[(size_t)(n0 + srow) * FINc + sseg * 16];
    const unsigned short* bsrc = &WbT[((size_t)(head * 128 + ob + srow)) * FINc + sseg * 16];
    const int rowbase = (wid & 1) * 32, colbase = (wid >> 1) * 32;
    f16v acc = {};
    for (int fc = 0; fc < FINc; fc += 64) {
        us8 a0 = *(const us8*)(asrc + fc), a1 = *(const us8*)(asrc + fc + 8);
        us8 b0 = *(const us8*)(bsrc + fc), b1 = *(const us8*)(bsrc + fc + 8);
        __syncthreads();
        {
            int byt = (sseg * 32) ^ ((srow & 7) << 4);
            char* pa = Ax + srow * 128;
            *(us8*)(pa + byt) = a0;  *(us8*)(pa + (byt ^ 16)) = a1;
            char* pb = Bx + srow * 128;
            *(us8*)(pb + byt) = b0;  *(us8*)(pb + (byt ^ 16)) = b1;
        }
        __syncthreads();
#pragma unroll
        for (int ks = 0; ks < 4; ++ks) {
            int kb = ks * 32 + ((lane >> 5) << 4);
            int ar = rowbase + (lane & 31);
            bfrag af = *(const bfrag*)(Ax + ar * 128 + (kb ^ ((ar & 7) << 4)));
            int bc = colbase + (lane & 31);
            bfrag bf = *(const bfrag*)(Bx + bc * 128 + (kb ^ ((bc & 7) << 4)));
            acc = __builtin_amdgcn_mfma_f32_32x32x16_bf16(af, bf, acc, 0, 0, 0);
        }
    }
    // epilogue: acc -> LDS (transposed access) -> hT[k][col][m]
    __syncthreads();
#pragma unroll
    for (int reg = 0; reg < 16; ++reg) {
        int row = rowbase + (reg & 3) + 8 * (reg >> 2) + 4 * (lane >> 5);
        int col = colbase + (lane & 31);
        *(unsigned short*)(Ax + row * 128 + ((col * 2) ^ ((row & 7) << 4))) = f2bf(acc[reg]);
    }
    __syncthreads();
    {
        int col = t >> 2, mseg = (t & 3) * 16;
        alignas(16) unsigned short buf[16];
#pragma unroll
        for (int j = 0; j < 16; ++j) {
            int r = mseg + j;
            buf[j] = *(const unsigned short*)(Ax + r * 128 + ((col * 2) ^ ((r & 7) << 4)));
        }
        unsigned short* dst = &hT[((size_t)(head * 128 + ob + col)) * NN + n0 + mseg];
        *(us8*)dst       = *(const us8*)&buf[0];
        *(us8*)(dst + 8) = *(const us8*)&buf[8];
    }
}

// ---------------- kernel 3: ei[n,k], ejT[k,n] (pre-scaled by log2e) ----------------
__global__ __launch_bounds__(256) void e2_kernel(const unsigned short* __restrict__ hT,
                                                 const float* __restrict__ a,
                                                 float* __restrict__ ei,
                                                 float* __restrict__ ejT) {
    __shared__ float as[128], ad[128];
    __shared__ float pim[4][64], pjm[4][64];
    const int t = threadIdx.x;
    const int k = blockIdx.x >> 6;
    const int m0 = (blockIdx.x & 63) * 64;
    if (t < 128) as[t] = a[k * 256 + t] * LOG2E;
    else         ad[t - 128] = a[k * 256 + t] * LOG2E;
    __syncthreads();
    const int ml = t & 63, q = t >> 6;
    const unsigned short* src = &hT[((size_t)k * FOUTc + q * 32) * NN + m0 + ml];
    float si = 0.f, sj = 0.f;
#pragma unroll 8
    for (int c = 0; c < 32; ++c) {
        float v = bf2f(src[(size_t)c * NN]);
        si += v * as[q * 32 + c];
        sj += v * ad[q * 32 + c];
    }
    pim[q][ml] = si; pjm[q][ml] = sj;
    __syncthreads();
    if (t < 64) {
        ei[(m0 + t) * KHc + k]   = pim[0][t] + pim[1][t] + pim[2][t] + pim[3][t];
        ejT[(size_t)k * NN + m0 + t] = pjm[0][t] + pjm[1][t] + pjm[2][t] + pjm[3][t];
    }
}

// ---------------- kernel 4: out = softmax(P) @ H, denom fused ----------------
// 32 rows x 128 cols per block, 512 blocks (2/CU), XCD-chunked swizzle
__global__ __launch_bounds__(256) void out_mfma_kernel(const unsigned* __restrict__ bits,
                                                       const float* __restrict__ ei,
                                                       const float* __restrict__ ejT,
                                                       const unsigned short* __restrict__ hT,
                                                       float* __restrict__ out) {
    __shared__ char P_lds[32 * 128];
    __shared__ char Ht_lds[128 * 128];
    __shared__ float eiL[32];
    __shared__ float lsum[32];
    const int bid = blockIdx.x;
    const int nb  = (bid & 7) * 64 + (bid >> 3);   // bijective: 512 = 8*64
    const int k   = nb >> 7;
    const int n0  = (nb & 127) * 32;
    const int t = threadIdx.x, lane = t & 63, wid = t >> 6;
    const int colbase = wid * 32;
    const int pi = t >> 3, pjb = (t & 7) * 8;
    const int hr = t >> 1, hoff = (t & 1) * 64;
    if (t < 32) eiL[t] = ei[(n0 + t) * KHc + k];
    const unsigned short* hTk = hT + (size_t)k * FOUTc * NN;
    const float* ejp = &ejT[(size_t)k * NN];
    const unsigned* brow = &bits[(size_t)(n0 + pi) * 128];
    f16v acc = {};
    float psum = 0.f;

    for (int mc = 0; mc < NN; mc += 64) {
        // prefetch to regs (overlaps barrier)
        f4 ejv0 = *(const f4*)&ejp[mc + pjb];
        f4 ejv1 = *(const f4*)&ejp[mc + pjb + 4];
        unsigned bw = brow[(mc + pjb) >> 5] >> (pjb & 24);
        us8 hg[4];
        const unsigned short* src = &hTk[(size_t)hr * NN + mc + (hoff >> 1)];
#pragma unroll
        for (int c = 0; c < 4; ++c) hg[c] = *(const us8*)(src + c * 8);
        __syncthreads();
        // P tile 32x64 (values = exp2(lrelu-scaled score)), fp32 row-sum kept
        {
            float eiv = eiL[pi];
            float p[8];
#pragma unroll
            for (int j = 0; j < 8; ++j) {
                float sc = eiv + (j < 4 ? ejv0[j] : ejv1[j - 4]);
                sc = fmaxf(sc, ALPHA * sc);
                float pp = exp2f(sc);
                pp = ((bw >> j) & 1) ? pp : 0.f;
                p[j] = pp;
                psum += pp;
            }
            union { unsigned u[4]; us8 v; } pk;
#pragma unroll
            for (int j = 0; j < 4; ++j) {
                float2 fp; fp.x = p[2 * j]; fp.y = p[2 * j + 1];
                __hip_bfloat162 b2 = __float22bfloat162_rn(fp);
                pk.u[j] = *reinterpret_cast<unsigned*>(&b2);
            }
            *(us8*)(P_lds + pi * 128 + ((pjb * 2) ^ ((pi & 7) << 4))) = pk.v;
        }
        // Ht tile 128x64
        {
            char* base = Ht_lds + hr * 128;
#pragma unroll
            for (int c = 0; c < 4; ++c) {
                int b = (hoff + c * 16) ^ ((hr & 7) << 4);
                *(us8*)(base + b) = hg[c];
            }
        }
        __syncthreads();
#pragma unroll
        for (int ks = 0; ks < 4; ++ks) {
            int kb = ks * 32 + ((lane >> 5) << 4);
            int ar = lane & 31;
            bfrag af = *(const bfrag*)(P_lds + ar * 128 + (kb ^ ((ar & 7) << 4)));
            int bc = colbase + (lane & 31);
            bfrag bf = *(const bfrag*)(Ht_lds + bc * 128 + (kb ^ ((bc & 7) << 4)));
            acc = __builtin_amdgcn_mfma_f32_32x32x16_bf16(af, bf, acc, 0, 0, 0);
        }
    }
    // fused denominator: reduce 8 threads per row
    psum += __shfl_xor(psum, 1);
    psum += __shfl_xor(psum, 2);
    psum += __shfl_xor(psum, 4);
    if ((t & 7) == 0) lsum[pi] = psum;
    __syncthreads();
    if (t < 32) lsum[t] = 1.0f / lsum[t];
    __syncthreads();
#pragma unroll
    for (int reg = 0; reg < 16; ++reg) {
        int row = (reg & 3) + 8 * (reg >> 2) + 4 * (lane >> 5);
        out[(size_t)(n0 + row) * KFc + k * FOUTc + colbase + (lane & 31)] = acc[reg] * lsum[row];
    }
}

extern "C" void kernel_launch(void* const* d_in, const int* in_sizes, int n_in,
                              void* d_out, int out_size, void* d_ws, size_t ws_size,
                              hipStream_t stream) {
    const float* x   = (const float*)d_in[0];
    const int*   adj = (const int*)d_in[1];
    const float* W   = (const float*)d_in[2];
    const float* a   = (const float*)d_in[3];
    float* out = (float*)d_out;
    char* ws = (char*)d_ws;

    unsigned short* hT   = (unsigned short*)ws;                 // 4 MB
    unsigned short* xb   = (unsigned short*)(ws + (4u << 20));  // 4 MB
    unsigned short* WbT  = (unsigned short*)(ws + (8u << 20));  // 0.5 MB
    unsigned*       bits = (unsigned*)(ws + (9u << 20));        // 2 MB
    float*          ei   = (float*)(ws + (11u << 20));          // 64 KB
    float*          ejT  = ei + (size_t)NN * KHc;               // 64 KB

    bits_kernel<<<(NN * NN) / 256, 256, 0, stream>>>(adj, bits);
    prep_kernel<<<1026, 256, 0, stream>>>(x, W, xb, WbT);
    gemmh_kernel<<<dim3(8, 64), 256, 0, stream>>>(xb, WbT, hT);
    e2_kernel<<<256, 256, 0, stream>>>(hT, a, ei, ejT);
    out_mfma_kernel<<<512, 256, 0, stream>>>(bits, ei, ejT, hT, out);
}

// Round 5
// 109.952 us; speedup vs baseline: 1.1771x; 1.1771x over previous
//
#include <hip/hip_runtime.h>
#include <hip/hip_bf16.h>

typedef float f4 __attribute__((ext_vector_type(4)));
typedef unsigned short us8 __attribute__((ext_vector_type(8)));
typedef short bfrag __attribute__((ext_vector_type(8)));     // 8 bf16
typedef float f16v __attribute__((ext_vector_type(16)));

constexpr int NN   = 4096;
constexpr int FINc = 512;
constexpr int FOUTc= 128;
constexpr int KHc  = 4;
constexpr int KFc  = 512;
constexpr float ALPHA = 0.2f;
constexpr float LOG2E = 1.44269504088896340736f;

static __device__ __forceinline__ unsigned short f2bf(float f) {
    unsigned u = __float_as_uint(f);
    return (unsigned short)((u + 0x7fffu + ((u >> 16) & 1u)) >> 16);   // RNE
}
static __device__ __forceinline__ float bf2f(unsigned short u) {
    return __uint_as_float(((unsigned)u) << 16);
}
static __device__ __forceinline__ bfrag us2bf(us8 v) {
    union { us8 u; bfrag s; } cv; cv.u = v; return cv.s;
}

// hB fragment layout (bf16): per head k, per 64-m chunk mc:
//   byte = k*1048576 + mc*16384 + ks*4096 + lg*2048 + col*16 + j*2
// where m = ks*16 + lg*8 + j  (ks in [0,4), lg in [0,2), j in [0,8)), col in [0,128)

// ---------------- kernel 0: adj -> bitmask ----------------
__global__ __launch_bounds__(256) void bits_kernel(const int* __restrict__ adj,
                                                   unsigned* __restrict__ bits) {
    size_t idx = (size_t)blockIdx.x * 256 + threadIdx.x;
    unsigned long long b = __ballot(adj[idx] != 0);
    int l = threadIdx.x & 63;
    if (l == 0)       bits[idx >> 5] = (unsigned)b;
    else if (l == 32) bits[idx >> 5] = (unsigned)(b >> 32);
}

// ---------------- kernel 1: cast x->xb (bf16); W -> WbT[k][o][f] (bf16, tiled transpose) ----------------
__global__ __launch_bounds__(256) void prep_kernel(const float* __restrict__ x,
                                                   const float* __restrict__ W,
                                                   unsigned short* __restrict__ xb,
                                                   unsigned short* __restrict__ WbT) {
    const int b = blockIdx.x, t = threadIdx.x;
    if (b < 1024) {                       // x: 2M elements, 8 per thread
        size_t base = ((size_t)b * 256 + t) * 8;
        f4 v0 = *(const f4*)&x[base];
        f4 v1 = *(const f4*)&x[base + 4];
        us8 o;
#pragma unroll
        for (int j = 0; j < 4; ++j) { o[j] = f2bf(v0[j]); o[4 + j] = f2bf(v1[j]); }
        *(us8*)&xb[base] = o;
    } else {                              // W transpose: 32 blocks, 64f x 128o tiles
        __shared__ float tile[64 * 132];
        const int wb = b - 1024;
        const int k = wb >> 3, f0 = (wb & 7) * 64;
#pragma unroll
        for (int p = 0; p < 8; ++p) {
            int fl = p * 8 + (t >> 5);
            int oc = (t & 31) * 4;
            *(f4*)&tile[fl * 132 + oc] =
                *(const f4*)&W[(size_t)k * 65536 + (size_t)(f0 + fl) * 128 + oc];
        }
        __syncthreads();
        const int o = t >> 1, fh = (t & 1) * 32;
        alignas(16) unsigned short buf[32];
#pragma unroll
        for (int j = 0; j < 32; ++j) buf[j] = f2bf(tile[(fh + j) * 132 + o]);
        unsigned short* dst = &WbT[((size_t)k * 128 + o) * FINc + f0 + fh];
#pragma unroll
        for (int c = 0; c < 4; ++c) *(us8*)(dst + c * 8) = *(const us8*)&buf[c * 8];
    }
}

// ---------------- kernel 2: hB = (x @ W) bf16, fragment-packed ----------------
__global__ __launch_bounds__(256) void gemmh_kernel(const unsigned short* __restrict__ xb,
                                                    const unsigned short* __restrict__ WbT,
                                                    unsigned short* __restrict__ hB) {
    __shared__ char Ax[64 * 128];
    __shared__ char Bx[64 * 128];
    const int t = threadIdx.x, wid = t >> 6, lane = t & 63;
    const int c0 = blockIdx.x * 64, n0 = blockIdx.y * 64;
    const int head = c0 >> 7, ob = c0 & 127;
    const int srow = t >> 2, sseg = t & 3;
    const unsigned short* asrc = &xb[(size_t)(n0 + srow) * FINc + sseg * 16];
    const unsigned short* bsrc = &WbT[((size_t)(head * 128 + ob + srow)) * FINc + sseg * 16];
    const int rowbase = (wid & 1) * 32, colbase = (wid >> 1) * 32;
    f16v acc = {};
    for (int fc = 0; fc < FINc; fc += 64) {
        us8 a0 = *(const us8*)(asrc + fc), a1 = *(const us8*)(asrc + fc + 8);
        us8 b0 = *(const us8*)(bsrc + fc), b1 = *(const us8*)(bsrc + fc + 8);
        __syncthreads();
        {
            int byt = (sseg * 32) ^ ((srow & 7) << 4);
            char* pa = Ax + srow * 128;
            *(us8*)(pa + byt) = a0;  *(us8*)(pa + (byt ^ 16)) = a1;
            char* pb = Bx + srow * 128;
            *(us8*)(pb + byt) = b0;  *(us8*)(pb + (byt ^ 16)) = b1;
        }
        __syncthreads();
#pragma unroll
        for (int ks = 0; ks < 4; ++ks) {
            int kb = ks * 32 + ((lane >> 5) << 4);
            int ar = rowbase + (lane & 31);
            bfrag af = *(const bfrag*)(Ax + ar * 128 + (kb ^ ((ar & 7) << 4)));
            int bc = colbase + (lane & 31);
            bfrag bf = *(const bfrag*)(Bx + bc * 128 + (kb ^ ((bc & 7) << 4)));
            acc = __builtin_amdgcn_mfma_f32_32x32x16_bf16(af, bf, acc, 0, 0, 0);
        }
    }
    // epilogue: acc -> LDS (bf16, swizzled) -> hB fragment-packed
    __syncthreads();
#pragma unroll
    for (int reg = 0; reg < 16; ++reg) {
        int row = rowbase + (reg & 3) + 8 * (reg >> 2) + 4 * (lane >> 5);   // m-local
        int col = colbase + (lane & 31);                                    // col-local [0,64)
        *(unsigned short*)(Ax + row * 128 + ((col * 2) ^ ((row & 7) << 4))) = f2bf(acc[reg]);
    }
    __syncthreads();
    {
        const int col_l = t & 63;
        unsigned short* dstbase = hB + (size_t)head * 524288 + (size_t)(n0 >> 6) * 8192
                                     + (size_t)(ob + col_l) * 8;
#pragma unroll
        for (int g = 0; g < 2; ++g) {
            int o8 = (t >> 6) + g * 4;              // m-octet 0..7
            int ks = o8 >> 1, lg = o8 & 1;
            alignas(16) unsigned short buf[8];
#pragma unroll
            for (int j = 0; j < 8; ++j) {
                int r = o8 * 8 + j;
                buf[j] = *(const unsigned short*)(Ax + r * 128 + ((col_l * 2) ^ ((r & 7) << 4)));
            }
            *(us8*)(dstbase + ks * 2048 + lg * 1024) = *(const us8*)buf;
        }
    }
}

// ---------------- kernel 3: ei[n,k], ejT[k,n] from hB (pre-scaled by log2e) ----------------
__global__ __launch_bounds__(256) void e2_kernel(const unsigned short* __restrict__ hB,
                                                 const float* __restrict__ a,
                                                 float* __restrict__ ei,
                                                 float* __restrict__ ejT) {
    __shared__ unsigned short hs[8192];     // one 64-m chunk, 16KB
    __shared__ float as[128], ad[128];
    __shared__ float pim[4][64], pjm[4][64];
    const int t = threadIdx.x;
    const int k = blockIdx.x >> 6;
    const int mc = blockIdx.x & 63;
    if (t < 128) as[t] = a[k * 256 + t] * LOG2E;
    else         ad[t - 128] = a[k * 256 + t] * LOG2E;
    const unsigned short* src = hB + ((size_t)k * 64 + mc) * 8192;
#pragma unroll
    for (int i = 0; i < 4; ++i) {
        int off = i * 2048 + t * 8;
        *(us8*)&hs[off] = *(const us8*)&src[off];
    }
    __syncthreads();
    const int m = t & 63, wq = t >> 6;
    const int base = (m >> 4) * 2048 + ((m >> 3) & 1) * 1024 + (m & 7);
    float si = 0.f, sj = 0.f;
#pragma unroll
    for (int cc = 0; cc < 32; ++cc) {
        int c = wq * 32 + cc;
        float v = bf2f(hs[base + c * 8]);
        si += v * as[c];
        sj += v * ad[c];
    }
    pim[wq][m] = si; pjm[wq][m] = sj;
    __syncthreads();
    if (t < 64) {
        ei[(mc * 64 + t) * KHc + k]        = pim[0][t] + pim[1][t] + pim[2][t] + pim[3][t];
        ejT[(size_t)k * NN + mc * 64 + t]  = pjm[0][t] + pjm[1][t] + pjm[2][t] + pjm[3][t];
    }
}

// ---------------- kernel 4: out = softmax(P) @ H; B-frags direct from global ----------------
// 1024 blocks (4/CU): 32 rows x 64 cols, full m; waves = 2 col-tiles x 2 K-halves
__global__ __launch_bounds__(256) void out_mfma_kernel(const unsigned* __restrict__ bits,
                                                       const float* __restrict__ ei,
                                                       const float* __restrict__ ejT,
                                                       const unsigned short* __restrict__ hB,
                                                       float* __restrict__ out) {
    __shared__ char P_lds[32 * 128];
    __shared__ float eiL[32];
    __shared__ float lsum[32];
    __shared__ float xbuf[2][16][64];
    const int bid = blockIdx.x;
    const int nb  = (bid & 7) * 128 + (bid >> 3);   // bijective: 1024 = 8*128
    const int k   = nb >> 8;
    const int rt  = (nb & 255) >> 1;
    const int ch  = nb & 1;
    const int n0  = rt * 32;
    const int t = threadIdx.x, lane = t & 63, wid = t >> 6;
    const int ct = wid & 1, kh = wid >> 1;
    const int pi = t >> 3, pjb = (t & 7) * 8;
    if (t < 32) eiL[t] = ei[(n0 + t) * KHc + k];
    const float* ejp = &ejT[(size_t)k * NN];
    const unsigned* brow = &bits[(size_t)(n0 + pi) * 128];
    const char* hbase = (const char*)hB + (size_t)k * 1048576 + kh * 8192
                        + (size_t)(lane >> 5) * 2048
                        + (size_t)(ch * 64 + ct * 32 + (lane & 31)) * 16;
    f16v acc = {};
    float psum = 0.f;

    for (int mc = 0; mc < NN; mc += 64) {
        // prefetch to regs (hides latency across both barriers)
        f4 ejv0 = *(const f4*)&ejp[mc + pjb];
        f4 ejv1 = *(const f4*)&ejp[mc + pjb + 4];
        unsigned bw = brow[(mc + pjb) >> 5] >> (pjb & 24);
        const char* hc = hbase + (size_t)(mc >> 6) * 16384;
        us8 hg0 = *(const us8*)(hc);
        us8 hg1 = *(const us8*)(hc + 4096);
        __syncthreads();                      // prev-iter P reads complete
        {   // P tile 32x64: p = exp2(lrelu(ei+ej)) masked; fp32 row-sum kept
            float eiv = eiL[pi];
            float p[8];
#pragma unroll
            for (int j = 0; j < 8; ++j) {
                float sc = eiv + (j < 4 ? ejv0[j] : ejv1[j - 4]);
                sc = fmaxf(sc, ALPHA * sc);
                float pp = exp2f(sc);
                pp = ((bw >> j) & 1) ? pp : 0.f;
                p[j] = pp;
                psum += pp;
            }
            union { unsigned u[4]; us8 v; } pk;
#pragma unroll
            for (int j = 0; j < 4; ++j) {
                float2 fp; fp.x = p[2 * j]; fp.y = p[2 * j + 1];
                __hip_bfloat162 b2 = __float22bfloat162_rn(fp);
                pk.u[j] = *reinterpret_cast<unsigned*>(&b2);
            }
            *(us8*)(P_lds + pi * 128 + ((pjb * 2) ^ ((pi & 7) << 4))) = pk.v;
        }
        __syncthreads();                      // P ready
        {
            int ar = lane & 31;
            int kb0 = kh * 64 + ((lane >> 5) << 4);
            bfrag af0 = *(const bfrag*)(P_lds + ar * 128 + (kb0 ^ ((ar & 7) << 4)));
            acc = __builtin_amdgcn_mfma_f32_32x32x16_bf16(af0, us2bf(hg0), acc, 0, 0, 0);
            int kb1 = kb0 + 32;
            bfrag af1 = *(const bfrag*)(P_lds + ar * 128 + (kb1 ^ ((ar & 7) << 4)));
            acc = __builtin_amdgcn_mfma_f32_32x32x16_bf16(af1, us2bf(hg1), acc, 0, 0, 0);
        }
    }
    // fused denominator: 8 threads per row
    psum += __shfl_xor(psum, 1);
    psum += __shfl_xor(psum, 2);
    psum += __shfl_xor(psum, 4);
    if ((t & 7) == 0) lsum[pi] = psum;
    __syncthreads();
    if (t < 32) lsum[t] = 1.0f / lsum[t];
    if (kh == 1) {
#pragma unroll
        for (int reg = 0; reg < 16; ++reg) xbuf[ct][reg][lane] = acc[reg];
    }
    __syncthreads();
    if (kh == 0) {
#pragma unroll
        for (int reg = 0; reg < 16; ++reg) {
            int row = (reg & 3) + 8 * (reg >> 2) + 4 * (lane >> 5);
            float v = (acc[reg] + xbuf[ct][reg][lane]) * lsum[row];
            out[(size_t)(n0 + row) * KFc + k * FOUTc + ch * 64 + ct * 32 + (lane & 31)] = v;
        }
    }
}

extern "C" void kernel_launch(void* const* d_in, const int* in_sizes, int n_in,
                              void* d_out, int out_size, void* d_ws, size_t ws_size,
                              hipStream_t stream) {
    const float* x   = (const float*)d_in[0];
    const int*   adj = (const int*)d_in[1];
    const float* W   = (const float*)d_in[2];
    const float* a   = (const float*)d_in[3];
    float* out = (float*)d_out;
    char* ws = (char*)d_ws;

    unsigned short* hB   = (unsigned short*)ws;                 // 4 MB (fragment-packed h)
    unsigned short* xb   = (unsigned short*)(ws + (4u << 20));  // 4 MB
    unsigned short* WbT  = (unsigned short*)(ws + (8u << 20));  // 0.5 MB
    unsigned*       bits = (unsigned*)(ws + (9u << 20));        // 2 MB
    float*          ei   = (float*)(ws + (11u << 20));          // 64 KB
    float*          ejT  = ei + (size_t)NN * KHc;               // 64 KB

    bits_kernel<<<(NN * NN) / 256, 256, 0, stream>>>(adj, bits);
    prep_kernel<<<1056, 256, 0, stream>>>(x, W, xb, WbT);
    gemmh_kernel<<<dim3(8, 64), 256, 0, stream>>>(xb, WbT, hB);
    e2_kernel<<<256, 256, 0, stream>>>(hB, a, ei, ejT);
    out_mfma_kernel<<<1024, 256, 0, stream>>>(bits, ei, ejT, hB, out);
}

// Round 6
// 102.775 us; speedup vs baseline: 1.2593x; 1.0698x over previous
//
#include <hip/hip_runtime.h>
#include <hip/hip_bf16.h>

typedef float f4 __attribute__((ext_vector_type(4)));
typedef unsigned short us8 __attribute__((ext_vector_type(8)));
typedef short bfrag __attribute__((ext_vector_type(8)));     // 8 bf16
typedef float f16v __attribute__((ext_vector_type(16)));

constexpr int NN   = 4096;
constexpr int FINc = 512;
constexpr int FOUTc= 128;
constexpr int KHc  = 4;
constexpr int KFc  = 512;
constexpr float ALPHA = 0.2f;
constexpr float LOG2E = 1.44269504088896340736f;

static __device__ __forceinline__ unsigned short f2bf(float f) {
    unsigned u = __float_as_uint(f);
    return (unsigned short)((u + 0x7fffu + ((u >> 16) & 1u)) >> 16);   // RNE
}
static __device__ __forceinline__ float bf2f(unsigned short u) {
    return __uint_as_float(((unsigned)u) << 16);
}
static __device__ __forceinline__ bfrag us2bf(us8 v) {
    union { us8 u; bfrag s; } cv; cv.u = v; return cv.s;
}

// hB fragment layout (bf16): per head k, per 64-m chunk mc:
//   byte = k*1048576 + mc*16384 + ks*4096 + lg*2048 + col*16 + j*2
// where m = ks*16 + lg*8 + j  (ks in [0,4), lg in [0,2), j in [0,8)), col in [0,128)

// ---------------- kernel 0: fused prep: adj->bits | x->xb | W->WbT ----------------
__global__ __launch_bounds__(256) void prep_kernel(const int* __restrict__ adj,
                                                   const float* __restrict__ x,
                                                   const float* __restrict__ W,
                                                   unsigned* __restrict__ bits,
                                                   unsigned short* __restrict__ xb,
                                                   unsigned short* __restrict__ WbT) {
    __shared__ float tile[32 * 132];
    const int b = blockIdx.x, t = threadIdx.x;
    if (b < 65536) {                      // adj -> bitmask
        size_t idx = (size_t)b * 256 + t;
        unsigned long long bl = __ballot(adj[idx] != 0);
        int l = t & 63;
        if (l == 0)       bits[idx >> 5] = (unsigned)bl;
        else if (l == 32) bits[idx >> 5] = (unsigned)(bl >> 32);
    } else if (b < 65536 + 1024) {        // x cast: 8 per thread
        size_t base = ((size_t)(b - 65536) * 256 + t) * 8;
        f4 v0 = *(const f4*)&x[base];
        f4 v1 = *(const f4*)&x[base + 4];
        us8 o;
#pragma unroll
        for (int j = 0; j < 4; ++j) { o[j] = f2bf(v0[j]); o[4 + j] = f2bf(v1[j]); }
        *(us8*)&xb[base] = o;
    } else {                              // W transpose: 64 blocks, 32f x 128o tiles
        const int wb = b - 65536 - 1024;
        const int k = wb >> 4, f0 = (wb & 15) * 32;
#pragma unroll
        for (int p = 0; p < 4; ++p) {
            int fl = p * 8 + (t >> 5);
            int oc = (t & 31) * 4;
            *(f4*)&tile[fl * 132 + oc] =
                *(const f4*)&W[(size_t)k * 65536 + (size_t)(f0 + fl) * 128 + oc];
        }
        __syncthreads();
        const int o = t >> 1, fh = (t & 1) * 16;
        alignas(16) unsigned short buf[16];
#pragma unroll
        for (int j = 0; j < 16; ++j) buf[j] = f2bf(tile[(fh + j) * 132 + o]);
        unsigned short* dst = &WbT[((size_t)k * 128 + o) * FINc + f0 + fh];
        *(us8*)dst       = *(const us8*)&buf[0];
        *(us8*)(dst + 8) = *(const us8*)&buf[8];
    }
}

// ---------------- kernel 2: hB = (x @ W) bf16, fragment-packed ----------------
__global__ __launch_bounds__(256) void gemmh_kernel(const unsigned short* __restrict__ xb,
                                                    const unsigned short* __restrict__ WbT,
                                                    unsigned short* __restrict__ hB) {
    __shared__ char Ax[64 * 128];
    __shared__ char Bx[64 * 128];
    const int t = threadIdx.x, wid = t >> 6, lane = t & 63;
    const int c0 = blockIdx.x * 64, n0 = blockIdx.y * 64;
    const int head = c0 >> 7, ob = c0 & 127;
    const int srow = t >> 2, sseg = t & 3;
    const unsigned short* asrc = &xb[(size_t)(n0 + srow) * FINc + sseg * 16];
    const unsigned short* bsrc = &WbT[((size_t)(head * 128 + ob + srow)) * FINc + sseg * 16];
    const int rowbase = (wid & 1) * 32, colbase = (wid >> 1) * 32;
    f16v acc = {};
    for (int fc = 0; fc < FINc; fc += 64) {
        us8 a0 = *(const us8*)(asrc + fc), a1 = *(const us8*)(asrc + fc + 8);
        us8 b0 = *(const us8*)(bsrc + fc), b1 = *(const us8*)(bsrc + fc + 8);
        __syncthreads();
        {
            int byt = (sseg * 32) ^ ((srow & 7) << 4);
            char* pa = Ax + srow * 128;
            *(us8*)(pa + byt) = a0;  *(us8*)(pa + (byt ^ 16)) = a1;
            char* pb = Bx + srow * 128;
            *(us8*)(pb + byt) = b0;  *(us8*)(pb + (byt ^ 16)) = b1;
        }
        __syncthreads();
#pragma unroll
        for (int ks = 0; ks < 4; ++ks) {
            int kb = ks * 32 + ((lane >> 5) << 4);
            int ar = rowbase + (lane & 31);
            bfrag af = *(const bfrag*)(Ax + ar * 128 + (kb ^ ((ar & 7) << 4)));
            int bc = colbase + (lane & 31);
            bfrag bf = *(const bfrag*)(Bx + bc * 128 + (kb ^ ((bc & 7) << 4)));
            acc = __builtin_amdgcn_mfma_f32_32x32x16_bf16(af, bf, acc, 0, 0, 0);
        }
    }
    // epilogue: acc -> LDS (bf16, swizzled) -> hB fragment-packed
    __syncthreads();
#pragma unroll
    for (int reg = 0; reg < 16; ++reg) {
        int row = rowbase + (reg & 3) + 8 * (reg >> 2) + 4 * (lane >> 5);   // m-local
        int col = colbase + (lane & 31);                                    // col-local [0,64)
        *(unsigned short*)(Ax + row * 128 + ((col * 2) ^ ((row & 7) << 4))) = f2bf(acc[reg]);
    }
    __syncthreads();
    {
        const int col_l = t & 63;
        unsigned short* dstbase = hB + (size_t)head * 524288 + (size_t)(n0 >> 6) * 8192
                                     + (size_t)(ob + col_l) * 8;
#pragma unroll
        for (int g = 0; g < 2; ++g) {
            int o8 = (t >> 6) + g * 4;              // m-octet 0..7
            int ks = o8 >> 1, lg = o8 & 1;
            alignas(16) unsigned short buf[8];
#pragma unroll
            for (int j = 0; j < 8; ++j) {
                int r = o8 * 8 + j;
                buf[j] = *(const unsigned short*)(Ax + r * 128 + ((col_l * 2) ^ ((r & 7) << 4)));
            }
            *(us8*)(dstbase + ks * 2048 + lg * 1024) = *(const us8*)buf;
        }
    }
}

// ---------------- kernel 3: ei[n,k], ejT[k,n] from hB (pre-scaled by log2e) ----------------
__global__ __launch_bounds__(256) void e2_kernel(const unsigned short* __restrict__ hB,
                                                 const float* __restrict__ a,
                                                 float* __restrict__ ei,
                                                 float* __restrict__ ejT) {
    __shared__ unsigned short hs[8192];     // one 64-m chunk, 16KB
    __shared__ float as[128], ad[128];
    __shared__ float pim[4][64], pjm[4][64];
    const int t = threadIdx.x;
    const int k = blockIdx.x >> 6;
    const int mc = blockIdx.x & 63;
    if (t < 128) as[t] = a[k * 256 + t] * LOG2E;
    else         ad[t - 128] = a[k * 256 + t] * LOG2E;
    const unsigned short* src = hB + ((size_t)k * 64 + mc) * 8192;
#pragma unroll
    for (int i = 0; i < 4; ++i) {
        int off = i * 2048 + t * 8;
        *(us8*)&hs[off] = *(const us8*)&src[off];
    }
    __syncthreads();
    const int m = t & 63, wq = t >> 6;
    const int base = (m >> 4) * 2048 + ((m >> 3) & 1) * 1024 + (m & 7);
    float si = 0.f, sj = 0.f;
#pragma unroll
    for (int cc = 0; cc < 32; ++cc) {
        int c = wq * 32 + cc;
        float v = bf2f(hs[base + c * 8]);
        si += v * as[c];
        sj += v * ad[c];
    }
    pim[wq][m] = si; pjm[wq][m] = sj;
    __syncthreads();
    if (t < 64) {
        ei[(mc * 64 + t) * KHc + k]        = pim[0][t] + pim[1][t] + pim[2][t] + pim[3][t];
        ejT[(size_t)k * NN + mc * 64 + t]  = pjm[0][t] + pjm[1][t] + pjm[2][t] + pjm[3][t];
    }
}

// ---------------- kernel 4: out = softmax(P) @ H ----------------
// 512 blocks (2/CU): 32 rows x 128 cols (full head), full m; 4 waves = 4 col-tiles.
// P double-buffered (1 barrier/iter); denominator via ones-MFMA (no VALU psum).
__global__ __launch_bounds__(256) void out_mfma_kernel(const unsigned* __restrict__ bits,
                                                       const float* __restrict__ ei,
                                                       const float* __restrict__ ejT,
                                                       const unsigned short* __restrict__ hB,
                                                       float* __restrict__ out) {
    __shared__ char P_lds[2][32 * 128];
    __shared__ float eiL[32];
    __shared__ float lsum[32];
    const int bid = blockIdx.x;
    const int nb  = (bid & 7) * 64 + (bid >> 3);   // bijective: 512 = 8*64
    const int k   = nb >> 7;
    const int n0  = (nb & 127) * 32;
    const int t = threadIdx.x, lane = t & 63, wid = t >> 6;
    const int pi = t >> 3, pjb = (t & 7) * 8;
    if (t < 32) eiL[t] = ei[(n0 + t) * KHc + k];
    const float* ejp = &ejT[(size_t)k * NN];
    const unsigned* brow = &bits[(size_t)(n0 + pi) * 128];
    const char* hbase = (const char*)hB + (size_t)k * 1048576
                        + (size_t)(lane >> 5) * 2048
                        + (size_t)(wid * 32 + (lane & 31)) * 16;
    bfrag ones;
#pragma unroll
    for (int j = 0; j < 8; ++j) ones[j] = (short)0x3F80;   // bf16 1.0
    f16v acc = {};
    f16v accs = {};

    auto genP = [&](int mc2, char* dst) {
        f4 ejv0 = *(const f4*)&ejp[mc2 + pjb];
        f4 ejv1 = *(const f4*)&ejp[mc2 + pjb + 4];
        unsigned bw = brow[(mc2 + pjb) >> 5] >> (pjb & 24);
        float eiv = eiL[pi];
        float p[8];
#pragma unroll
        for (int j = 0; j < 8; ++j) {
            float sc = eiv + (j < 4 ? ejv0[j] : ejv1[j - 4]);
            sc = fmaxf(sc, ALPHA * sc);
            float pp = exp2f(sc);
            p[j] = ((bw >> j) & 1) ? pp : 0.f;
        }
        union { unsigned u[4]; us8 v; } pk;
#pragma unroll
        for (int j = 0; j < 4; ++j) {
            float2 fp; fp.x = p[2 * j]; fp.y = p[2 * j + 1];
            __hip_bfloat162 b2 = __float22bfloat162_rn(fp);
            pk.u[j] = *reinterpret_cast<unsigned*>(&b2);
        }
        *(us8*)(dst + pi * 128 + ((pjb * 2) ^ ((pi & 7) << 4))) = pk.v;
    };

    __syncthreads();                 // eiL visible
    genP(0, P_lds[0]);
    __syncthreads();                 // P[0] ready

    for (int mc = 0; mc < NN; mc += 64) {
        const int cur = (mc >> 6) & 1;
        // B-frags for this iter (issue early; latency hides under P-gen VALU)
        us8 hg[4];
        const char* hc = hbase + (size_t)(mc >> 6) * 16384;
#pragma unroll
        for (int ks = 0; ks < 4; ++ks) hg[ks] = *(const us8*)(hc + ks * 4096);
        // generate next P tile into the other buffer (overlaps MFMA below)
        if (mc + 64 < NN) genP(mc + 64, P_lds[cur ^ 1]);
        // MFMA: 4 k-steps; accs accumulates row-sums via B=ones
#pragma unroll
        for (int ks = 0; ks < 4; ++ks) {
            int ar = lane & 31;
            int kb = ks * 32 + ((lane >> 5) << 4);
            bfrag af = *(const bfrag*)(P_lds[cur] + ar * 128 + (kb ^ ((ar & 7) << 4)));
            acc  = __builtin_amdgcn_mfma_f32_32x32x16_bf16(af, us2bf(hg[ks]), acc, 0, 0, 0);
            accs = __builtin_amdgcn_mfma_f32_32x32x16_bf16(af, ones, accs, 0, 0, 0);
        }
        __syncthreads();             // P[cur] fully consumed; P[cur^1] fully written
    }
    // denominator: accs[reg] (any col) = row sum; wave 0 lanes 0/32 publish
    if (wid == 0 && (lane & 31) == 0) {
#pragma unroll
        for (int reg = 0; reg < 16; ++reg) {
            int row = (reg & 3) + 8 * (reg >> 2) + 4 * (lane >> 5);
            lsum[row] = accs[reg];
        }
    }
    __syncthreads();
    if (t < 32) lsum[t] = 1.0f / lsum[t];
    __syncthreads();
#pragma unroll
    for (int reg = 0; reg < 16; ++reg) {
        int row = (reg & 3) + 8 * (reg >> 2) + 4 * (lane >> 5);
        out[(size_t)(n0 + row) * KFc + k * FOUTc + wid * 32 + (lane & 31)] = acc[reg] * lsum[row];
    }
}

extern "C" void kernel_launch(void* const* d_in, const int* in_sizes, int n_in,
                              void* d_out, int out_size, void* d_ws, size_t ws_size,
                              hipStream_t stream) {
    const float* x   = (const float*)d_in[0];
    const int*   adj = (const int*)d_in[1];
    const float* W   = (const float*)d_in[2];
    const float* a   = (const float*)d_in[3];
    float* out = (float*)d_out;
    char* ws = (char*)d_ws;

    unsigned short* hB   = (unsigned short*)ws;                 // 4 MB (fragment-packed h)
    unsigned short* xb   = (unsigned short*)(ws + (4u << 20));  // 4 MB
    unsigned short* WbT  = (unsigned short*)(ws + (8u << 20));  // 0.5 MB
    unsigned*       bits = (unsigned*)(ws + (9u << 20));        // 2 MB
    float*          ei   = (float*)(ws + (11u << 20));          // 64 KB
    float*          ejT  = ei + (size_t)NN * KHc;               // 64 KB

    prep_kernel<<<65536 + 1024 + 64, 256, 0, stream>>>(adj, x, W, bits, xb, WbT);
    gemmh_kernel<<<dim3(8, 64), 256, 0, stream>>>(xb, WbT, hB);
    e2_kernel<<<256, 256, 0, stream>>>(hB, a, ei, ejT);
    out_mfma_kernel<<<512, 256, 0, stream>>>(bits, ei, ejT, hB, out);
}

// Round 7
// 94.518 us; speedup vs baseline: 1.3693x; 1.0874x over previous
//
#include <hip/hip_runtime.h>
#include <hip/hip_bf16.h>

typedef float f4 __attribute__((ext_vector_type(4)));
typedef unsigned short us8 __attribute__((ext_vector_type(8)));
typedef short bfrag __attribute__((ext_vector_type(8)));     // 8 bf16
typedef float f16v __attribute__((ext_vector_type(16)));

constexpr int NN   = 4096;
constexpr int FINc = 512;
constexpr int FOUTc= 128;
constexpr int KHc  = 4;
constexpr int KFc  = 512;
constexpr float ALPHA = 0.2f;
constexpr float LOG2E = 1.44269504088896340736f;

static __device__ __forceinline__ unsigned short f2bf(float f) {
    unsigned u = __float_as_uint(f);
    return (unsigned short)((u + 0x7fffu + ((u >> 16) & 1u)) >> 16);   // RNE
}
static __device__ __forceinline__ float bf2f(unsigned short u) {
    return __uint_as_float(((unsigned)u) << 16);
}
static __device__ __forceinline__ bfrag us2bf(us8 v) {
    union { us8 u; bfrag s; } cv; cv.u = v; return cv.s;
}

// hB fragment layout (bf16): per head k, per 64-m chunk mc:
//   byte = k*1048576 + mc*16384 + ks*4096 + lg*2048 + col*16 + j*2
// where m = ks*16 + lg*8 + j, col in [0,128)

// ---------------- kernel 0: fused prep: adj->bits | x->xb | W->WbT ----------------
__global__ __launch_bounds__(256) void prep_kernel(const int* __restrict__ adj,
                                                   const float* __restrict__ x,
                                                   const float* __restrict__ W,
                                                   unsigned* __restrict__ bits,
                                                   unsigned short* __restrict__ xb,
                                                   unsigned short* __restrict__ WbT) {
    __shared__ float tile[32 * 132];
    const int b = blockIdx.x, t = threadIdx.x;
    if (b < 65536) {                      // adj -> bitmask
        size_t idx = (size_t)b * 256 + t;
        unsigned long long bl = __ballot(adj[idx] != 0);
        int l = t & 63;
        if (l == 0)       bits[idx >> 5] = (unsigned)bl;
        else if (l == 32) bits[idx >> 5] = (unsigned)(bl >> 32);
    } else if (b < 65536 + 1024) {        // x cast: 8 per thread
        size_t base = ((size_t)(b - 65536) * 256 + t) * 8;
        f4 v0 = *(const f4*)&x[base];
        f4 v1 = *(const f4*)&x[base + 4];
        us8 o;
#pragma unroll
        for (int j = 0; j < 4; ++j) { o[j] = f2bf(v0[j]); o[4 + j] = f2bf(v1[j]); }
        *(us8*)&xb[base] = o;
    } else {                              // W transpose: 64 blocks, 32f x 128o tiles
        const int wb = b - 65536 - 1024;
        const int k = wb >> 4, f0 = (wb & 15) * 32;
#pragma unroll
        for (int p = 0; p < 4; ++p) {
            int fl = p * 8 + (t >> 5);
            int oc = (t & 31) * 4;
            *(f4*)&tile[fl * 132 + oc] =
                *(const f4*)&W[(size_t)k * 65536 + (size_t)(f0 + fl) * 128 + oc];
        }
        __syncthreads();
        const int o = t >> 1, fh = (t & 1) * 16;
        alignas(16) unsigned short buf[16];
#pragma unroll
        for (int j = 0; j < 16; ++j) buf[j] = f2bf(tile[(fh + j) * 132 + o]);
        unsigned short* dst = &WbT[((size_t)k * 128 + o) * FINc + f0 + fh];
        *(us8*)dst       = *(const us8*)&buf[0];
        *(us8*)(dst + 8) = *(const us8*)&buf[8];
    }
}

// ---------------- kernel 1: hB = (x @ W) bf16, fragment-packed ----------------
__global__ __launch_bounds__(256) void gemmh_kernel(const unsigned short* __restrict__ xb,
                                                    const unsigned short* __restrict__ WbT,
                                                    unsigned short* __restrict__ hB) {
    __shared__ char Ax[64 * 128];
    __shared__ char Bx[64 * 128];
    const int t = threadIdx.x, wid = t >> 6, lane = t & 63;
    const int c0 = blockIdx.x * 64, n0 = blockIdx.y * 64;
    const int head = c0 >> 7, ob = c0 & 127;
    const int srow = t >> 2, sseg = t & 3;
    const unsigned short* asrc = &xb[(size_t)(n0 + srow) * FINc + sseg * 16];
    const unsigned short* bsrc = &WbT[((size_t)(head * 128 + ob + srow)) * FINc + sseg * 16];
    const int rowbase = (wid & 1) * 32, colbase = (wid >> 1) * 32;
    f16v acc = {};
    for (int fc = 0; fc < FINc; fc += 64) {
        us8 a0 = *(const us8*)(asrc + fc), a1 = *(const us8*)(asrc + fc + 8);
        us8 b0 = *(const us8*)(bsrc + fc), b1 = *(const us8*)(bsrc + fc + 8);
        __syncthreads();
        {
            int byt = (sseg * 32) ^ ((srow & 7) << 4);
            char* pa = Ax + srow * 128;
            *(us8*)(pa + byt) = a0;  *(us8*)(pa + (byt ^ 16)) = a1;
            char* pb = Bx + srow * 128;
            *(us8*)(pb + byt) = b0;  *(us8*)(pb + (byt ^ 16)) = b1;
        }
        __syncthreads();
#pragma unroll
        for (int ks = 0; ks < 4; ++ks) {
            int kb = ks * 32 + ((lane >> 5) << 4);
            int ar = rowbase + (lane & 31);
            bfrag af = *(const bfrag*)(Ax + ar * 128 + (kb ^ ((ar & 7) << 4)));
            int bc = colbase + (lane & 31);
            bfrag bf = *(const bfrag*)(Bx + bc * 128 + (kb ^ ((bc & 7) << 4)));
            acc = __builtin_amdgcn_mfma_f32_32x32x16_bf16(af, bf, acc, 0, 0, 0);
        }
    }
    __syncthreads();
#pragma unroll
    for (int reg = 0; reg < 16; ++reg) {
        int row = rowbase + (reg & 3) + 8 * (reg >> 2) + 4 * (lane >> 5);
        int col = colbase + (lane & 31);
        *(unsigned short*)(Ax + row * 128 + ((col * 2) ^ ((row & 7) << 4))) = f2bf(acc[reg]);
    }
    __syncthreads();
    {
        const int col_l = t & 63;
        unsigned short* dstbase = hB + (size_t)head * 524288 + (size_t)(n0 >> 6) * 8192
                                     + (size_t)(ob + col_l) * 8;
#pragma unroll
        for (int g = 0; g < 2; ++g) {
            int o8 = (t >> 6) + g * 4;
            int ks = o8 >> 1, lg = o8 & 1;
            alignas(16) unsigned short buf[8];
#pragma unroll
            for (int j = 0; j < 8; ++j) {
                int r = o8 * 8 + j;
                buf[j] = *(const unsigned short*)(Ax + r * 128 + ((col_l * 2) ^ ((r & 7) << 4)));
            }
            *(us8*)(dstbase + ks * 2048 + lg * 1024) = *(const us8*)buf;
        }
    }
}

// ---------------- kernel 2: ei[n,k], ejT[k,n] from hB (pre-scaled by log2e) ----------------
__global__ __launch_bounds__(256) void e2_kernel(const unsigned short* __restrict__ hB,
                                                 const float* __restrict__ a,
                                                 float* __restrict__ ei,
                                                 float* __restrict__ ejT) {
    __shared__ unsigned short hs[8192];
    __shared__ float as[128], ad[128];
    __shared__ float pim[4][64], pjm[4][64];
    const int t = threadIdx.x;
    const int k = blockIdx.x >> 6;
    const int mc = blockIdx.x & 63;
    if (t < 128) as[t] = a[k * 256 + t] * LOG2E;
    else         ad[t - 128] = a[k * 256 + t] * LOG2E;
    const unsigned short* src = hB + ((size_t)k * 64 + mc) * 8192;
#pragma unroll
    for (int i = 0; i < 4; ++i) {
        int off = i * 2048 + t * 8;
        *(us8*)&hs[off] = *(const us8*)&src[off];
    }
    __syncthreads();
    const int m = t & 63, wq = t >> 6;
    const int base = (m >> 4) * 2048 + ((m >> 3) & 1) * 1024 + (m & 7);
    float si = 0.f, sj = 0.f;
#pragma unroll
    for (int cc = 0; cc < 32; ++cc) {
        int c = wq * 32 + cc;
        float v = bf2f(hs[base + c * 8]);
        si += v * as[c];
        sj += v * ad[c];
    }
    pim[wq][m] = si; pjm[wq][m] = sj;
    __syncthreads();
    if (t < 64) {
        ei[(mc * 64 + t) * KHc + k]        = pim[0][t] + pim[1][t] + pim[2][t] + pim[3][t];
        ejT[(size_t)k * NN + mc * 64 + t]  = pjm[0][t] + pjm[1][t] + pjm[2][t] + pjm[3][t];
    }
}

// ---------------- kernel 3: partial out = P @ H over half of m ----------------
// 1024 blocks (4/CU): block = (k, 32-row tile, m-half); 16 iters of 128-m chunks.
// ej/bits loads pipelined 1 iter ahead; accs (row sums) round-robin across waves.
__global__ __launch_bounds__(256, 4) void out_mfma_kernel(const unsigned* __restrict__ bits,
                                                          const float* __restrict__ ei,
                                                          const float* __restrict__ ejT,
                                                          const unsigned short* __restrict__ hB,
                                                          float* __restrict__ pacc,
                                                          float* __restrict__ psum) {
    __shared__ char P_lds[2][32 * 256];
    __shared__ float eiL[32];
    __shared__ float sums[4][32];
    const int bid = blockIdx.x;
    const int nb  = (bid & 7) * 128 + (bid >> 3);   // bijective: 1024 = 8*128
    const int k   = nb >> 8;
    const int rt  = (nb & 255) >> 1;
    const int hf  = nb & 1;
    const int n0  = rt * 32;
    const int mbase = hf * 2048;
    const int t = threadIdx.x, lane = t & 63, wid = t >> 6;
    const int pi = t >> 3, mjb = (t & 7) * 16;
    if (t < 32) eiL[t] = ei[(n0 + t) * KHc + k];
    const float* ejp = &ejT[(size_t)k * NN + mbase];
    const unsigned* brow = &bits[(size_t)(n0 + pi) * 128 + (mbase >> 5)];
    const char* hbase = (const char*)hB + (size_t)k * 1048576 + (size_t)(hf * 32) * 16384
                        + (size_t)(lane >> 5) * 2048
                        + (size_t)(wid * 32 + (lane & 31)) * 16;
    bfrag ones;
#pragma unroll
    for (int j = 0; j < 8; ++j) ones[j] = (short)0x3F80;   // bf16 1.0

    f4 ejc[4];
    unsigned bwc;
    auto ldchunk = [&](int c) {
        int base = c * 128 + mjb;
#pragma unroll
        for (int i = 0; i < 4; ++i) ejc[i] = *(const f4*)&ejp[base + i * 4];
        bwc = brow[base >> 5] >> (base & 16);
    };
    auto genP = [&](float eiv, char* dst) {
        char* base = dst + pi * 256;
#pragma unroll
        for (int g = 0; g < 2; ++g) {
            float p[8];
#pragma unroll
            for (int j = 0; j < 8; ++j) {
                int e = g * 8 + j;
                float sc = eiv + ejc[e >> 2][e & 3];
                sc = fmaxf(sc, ALPHA * sc);
                float pp = exp2f(sc);
                p[j] = ((bwc >> e) & 1) ? pp : 0.f;
            }
            union { unsigned u[4]; us8 v; } pk;
#pragma unroll
            for (int j = 0; j < 4; ++j) {
                float2 fp; fp.x = p[2 * j]; fp.y = p[2 * j + 1];
                __hip_bfloat162 b2 = __float22bfloat162_rn(fp);
                pk.u[j] = *reinterpret_cast<unsigned*>(&b2);
            }
            *(us8*)(base + ((mjb * 2 + g * 16) ^ ((pi & 7) << 4))) = pk.v;
        }
    };

    ldchunk(0);
    __syncthreads();                 // eiL visible
    const float eiv = eiL[pi];
    genP(eiv, P_lds[0]);
    ldchunk(1);
    __syncthreads();                 // P[0] ready
    f16v acc = {}, accs = {};

    for (int it = 0; it < 16; ++it) {
        const int cur = it & 1;
        us8 hg[8];
        const char* hc = hbase + (size_t)it * 32768;
#pragma unroll
        for (int s8 = 0; s8 < 8; ++s8) hg[s8] = *(const us8*)(hc + s8 * 4096);
        if (it < 15) genP(eiv, P_lds[cur ^ 1]);
        if (it < 14) ldchunk(it + 2);
        const bool doS = ((it & 3) == wid);
#pragma unroll
        for (int ks8 = 0; ks8 < 8; ++ks8) {
            int ar = lane & 31;
            int kb = ks8 * 32 + ((lane >> 5) << 4);
            bfrag af = *(const bfrag*)(P_lds[cur] + ar * 256 + (kb ^ ((ar & 7) << 4)));
            acc = __builtin_amdgcn_mfma_f32_32x32x16_bf16(af, us2bf(hg[ks8]), acc, 0, 0, 0);
            if (doS) accs = __builtin_amdgcn_mfma_f32_32x32x16_bf16(af, ones, accs, 0, 0, 0);
        }
        __syncthreads();
    }
    // publish per-wave row-sum quarters, write f32 partial acc
    if ((lane & 31) == 0) {
#pragma unroll
        for (int reg = 0; reg < 16; ++reg) {
            int row = (reg & 3) + 8 * (reg >> 2) + 4 * (lane >> 5);
            sums[wid][row] = accs[reg];
        }
    }
    float* pa = &pacc[(size_t)nb * 4096 + wid * 32 + (lane & 31)];
#pragma unroll
    for (int reg = 0; reg < 16; ++reg) {
        int row = (reg & 3) + 8 * (reg >> 2) + 4 * (lane >> 5);
        pa[row * 128] = acc[reg];
    }
    __syncthreads();
    if (t < 32) psum[nb * 32 + t] = sums[0][t] + sums[1][t] + sums[2][t] + sums[3][t];
}

// ---------------- kernel 4: combine halves, scale by 1/denominator ----------------
__global__ __launch_bounds__(256) void combine_kernel(const float* __restrict__ pacc,
                                                      const float* __restrict__ psum,
                                                      float* __restrict__ out) {
    const int b = blockIdx.x;            // 512: k*128 + rt
    const int k = b >> 7, rt = b & 127;
    const int t = threadIdx.x;
    const int row = t >> 3, cb = (t & 7) * 16;
    const float* a0 = &pacc[(size_t)(b * 2) * 4096 + row * 128 + cb];
    const float* a1 = a0 + 4096;
    float s = psum[(b * 2) * 32 + row] + psum[(b * 2 + 1) * 32 + row];
    float rinv = 1.0f / s;
    float* o = &out[(size_t)(rt * 32 + row) * KFc + k * FOUTc + cb];
#pragma unroll
    for (int c4 = 0; c4 < 4; ++c4) {
        f4 v0 = *(const f4*)(a0 + c4 * 4);
        f4 v1 = *(const f4*)(a1 + c4 * 4);
        f4 v;
#pragma unroll
        for (int j = 0; j < 4; ++j) v[j] = (v0[j] + v1[j]) * rinv;
        *(f4*)(o + c4 * 4) = v;
    }
}

extern "C" void kernel_launch(void* const* d_in, const int* in_sizes, int n_in,
                              void* d_out, int out_size, void* d_ws, size_t ws_size,
                              hipStream_t stream) {
    const float* x   = (const float*)d_in[0];
    const int*   adj = (const int*)d_in[1];
    const float* W   = (const float*)d_in[2];
    const float* a   = (const float*)d_in[3];
    float* out = (float*)d_out;
    char* ws = (char*)d_ws;

    // layout (23.25 MB): pacc aliases xb (dead after gemmh)
    unsigned short* hB   = (unsigned short*)ws;                  // 0..4 MB
    unsigned short* xb   = (unsigned short*)(ws + (4u << 20));   // 4..8 MB (dead after gemmh)
    float*          pacc = (float*)(ws + (4u << 20));            // 4..20 MB (written by out_mfma)
    unsigned short* WbT  = (unsigned short*)(ws + (20u << 20));  // 20..20.5 MB
    unsigned*       bits = (unsigned*)(ws + (21u << 20));        // 21..23 MB
    float*          ei   = (float*)(ws + (23u << 20));           // 64 KB
    float*          ejT  = ei + (size_t)NN * KHc;                // 64 KB
    float*          psum = ejT + (size_t)NN * KHc;               // 128 KB

    prep_kernel<<<65536 + 1024 + 64, 256, 0, stream>>>(adj, x, W, bits, xb, WbT);
    gemmh_kernel<<<dim3(8, 64), 256, 0, stream>>>(xb, WbT, hB);
    e2_kernel<<<256, 256, 0, stream>>>(hB, a, ei, ejT);
    out_mfma_kernel<<<1024, 256, 0, stream>>>(bits, ei, ejT, hB, pacc, psum);
    combine_kernel<<<512, 256, 0, stream>>>(pacc, psum, out);
}

// Round 10
// 79.392 us; speedup vs baseline: 1.6302x; 1.1905x over previous
//
#include <hip/hip_runtime.h>
#include <hip/hip_bf16.h>

typedef float f4 __attribute__((ext_vector_type(4)));
typedef int   i4 __attribute__((ext_vector_type(4)));
typedef unsigned short us8 __attribute__((ext_vector_type(8)));
typedef short bfrag __attribute__((ext_vector_type(8)));     // 8 bf16
typedef float f16v __attribute__((ext_vector_type(16)));

constexpr int NN   = 4096;
constexpr int FINc = 512;
constexpr int FOUTc= 128;
constexpr int KHc  = 4;
constexpr int KFc  = 512;
constexpr float ALPHA = 0.2f;
constexpr float LOG2E = 1.44269504088896340736f;

static __device__ __forceinline__ unsigned short f2bf(float f) {
    unsigned u = __float_as_uint(f);
    return (unsigned short)((u + 0x7fffu + ((u >> 16) & 1u)) >> 16);   // RNE
}
static __device__ __forceinline__ float bf2f(unsigned short u) {
    return __uint_as_float(((unsigned)u) << 16);
}
static __device__ __forceinline__ bfrag us2bf(us8 v) {
    union { us8 u; bfrag s; } cv; cv.u = v; return cv.s;
}

// hB fragment layout (bf16): per head k, per 64-m chunk mc:
//   byte = k*1048576 + mc*16384 + ks*4096 + lg*2048 + col*16 + j*2
// where m = ks*16 + lg*8 + j, col in [0,128)

// ---------------- kernel 0: prep: x->xb (bf16) | W -> WbT[k][o][f] ----------------
__global__ __launch_bounds__(256) void prep_kernel(const float* __restrict__ x,
                                                   const float* __restrict__ W,
                                                   unsigned short* __restrict__ xb,
                                                   unsigned short* __restrict__ WbT) {
    __shared__ float tile[32 * 132];
    const int b = blockIdx.x, t = threadIdx.x;
    if (b < 1024) {                       // x cast: 8 per thread
        size_t base = ((size_t)b * 256 + t) * 8;
        f4 v0 = *(const f4*)&x[base];
        f4 v1 = *(const f4*)&x[base + 4];
        us8 o;
#pragma unroll
        for (int j = 0; j < 4; ++j) { o[j] = f2bf(v0[j]); o[4 + j] = f2bf(v1[j]); }
        *(us8*)&xb[base] = o;
    } else {                              // W transpose: 64 blocks, 32f x 128o tiles
        const int wb = b - 1024;
        const int k = wb >> 4, f0 = (wb & 15) * 32;
#pragma unroll
        for (int p = 0; p < 4; ++p) {
            int fl = p * 8 + (t >> 5);
            int oc = (t & 31) * 4;
            *(f4*)&tile[fl * 132 + oc] =
                *(const f4*)&W[(size_t)k * 65536 + (size_t)(f0 + fl) * 128 + oc];
        }
        __syncthreads();
        const int o = t >> 1, fh = (t & 1) * 16;
        alignas(16) unsigned short buf[16];
#pragma unroll
        for (int j = 0; j < 16; ++j) buf[j] = f2bf(tile[(fh + j) * 132 + o]);
        unsigned short* dst = &WbT[((size_t)k * 128 + o) * FINc + f0 + fh];
        *(us8*)dst       = *(const us8*)&buf[0];
        *(us8*)(dst + 8) = *(const us8*)&buf[8];
    }
}

// ---------------- kernel 1: gemmh (blocks 0..511) | adj->bits (blocks 512..1535) ----------------
__global__ __launch_bounds__(256) void gemmh_bits_kernel(const unsigned short* __restrict__ xb,
                                                         const unsigned short* __restrict__ WbT,
                                                         const int* __restrict__ adj,
                                                         unsigned short* __restrict__ hB,
                                                         unsigned* __restrict__ bits) {
    __shared__ char Ax[64 * 128];
    __shared__ char Bx[64 * 128];
    const int b = blockIdx.x, t = threadIdx.x;
    if (b >= 512) {                       // ---- bits: 1024 blocks x 16384 ints ----
        size_t i0 = (size_t)(b - 512) * 16384 + (size_t)t * 64;
        const int* ap = adj + i0;
        unsigned long long bb = 0ull;
#pragma unroll
        for (int c = 0; c < 16; ++c) {
            i4 v = *(const i4*)(ap + c * 4);
            unsigned n = (v[0] != 0 ? 1u : 0u) | (v[1] != 0 ? 2u : 0u)
                       | (v[2] != 0 ? 4u : 0u) | (v[3] != 0 ? 8u : 0u);
            bb |= (unsigned long long)n << (c * 4);
        }
        *(unsigned long long*)&bits[i0 >> 5] = bb;
        return;
    }
    const int wid = t >> 6, lane = t & 63;
    const int c0 = (b & 7) * 64, n0 = (b >> 3) * 64;
    const int head = c0 >> 7, ob = c0 & 127;
    const int srow = t >> 2, sseg = t & 3;
    const unsigned short* asrc = &xb[(size_t)(n0 + srow) * FINc + sseg * 16];
    const unsigned short* bsrc = &WbT[((size_t)(head * 128 + ob + srow)) * FINc + sseg * 16];
    const int rowbase = (wid & 1) * 32, colbase = (wid >> 1) * 32;
    f16v acc = {};
    for (int fc = 0; fc < FINc; fc += 64) {
        us8 a0 = *(const us8*)(asrc + fc), a1 = *(const us8*)(asrc + fc + 8);
        us8 b0 = *(const us8*)(bsrc + fc), b1 = *(const us8*)(bsrc + fc + 8);
        __syncthreads();
        {
            int byt = (sseg * 32) ^ ((srow & 7) << 4);
            char* pa = Ax + srow * 128;
            *(us8*)(pa + byt) = a0;  *(us8*)(pa + (byt ^ 16)) = a1;
            char* pb = Bx + srow * 128;
            *(us8*)(pb + byt) = b0;  *(us8*)(pb + (byt ^ 16)) = b1;
        }
        __syncthreads();
#pragma unroll
        for (int ks = 0; ks < 4; ++ks) {
            int kb = ks * 32 + ((lane >> 5) << 4);
            int ar = rowbase + (lane & 31);
            bfrag af = *(const bfrag*)(Ax + ar * 128 + (kb ^ ((ar & 7) << 4)));
            int bc = colbase + (lane & 31);
            bfrag bf = *(const bfrag*)(Bx + bc * 128 + (kb ^ ((bc & 7) << 4)));
            acc = __builtin_amdgcn_mfma_f32_32x32x16_bf16(af, bf, acc, 0, 0, 0);
        }
    }
    __syncthreads();
#pragma unroll
    for (int reg = 0; reg < 16; ++reg) {
        int row = rowbase + (reg & 3) + 8 * (reg >> 2) + 4 * (lane >> 5);
        int col = colbase + (lane & 31);
        *(unsigned short*)(Ax + row * 128 + ((col * 2) ^ ((row & 7) << 4))) = f2bf(acc[reg]);
    }
    __syncthreads();
    {
        const int col_l = t & 63;
        unsigned short* dstbase = hB + (size_t)head * 524288 + (size_t)(n0 >> 6) * 8192
                                     + (size_t)(ob + col_l) * 8;
#pragma unroll
        for (int g = 0; g < 2; ++g) {
            int o8 = (t >> 6) + g * 4;
            int ks = o8 >> 1, lg = o8 & 1;
            alignas(16) unsigned short buf[8];
#pragma unroll
            for (int j = 0; j < 8; ++j) {
                int r = o8 * 8 + j;
                buf[j] = *(const unsigned short*)(Ax + r * 128 + ((col_l * 2) ^ ((r & 7) << 4)));
            }
            *(us8*)(dstbase + ks * 2048 + lg * 1024) = *(const us8*)buf;
        }
    }
}

// ---------------- kernel 2: ei[n,k], ejT[k,n] from hB (pre-scaled by log2e) ----------------
__global__ __launch_bounds__(256) void e2_kernel(const unsigned short* __restrict__ hB,
                                                 const float* __restrict__ a,
                                                 float* __restrict__ ei,
                                                 float* __restrict__ ejT) {
    __shared__ unsigned short hs[8192];
    __shared__ float as[128], ad[128];
    __shared__ float pim[4][64], pjm[4][64];
    const int t = threadIdx.x;
    const int k = blockIdx.x >> 6;
    const int mc = blockIdx.x & 63;
    if (t < 128) as[t] = a[k * 256 + t] * LOG2E;
    else         ad[t - 128] = a[k * 256 + t] * LOG2E;
    const unsigned short* src = hB + ((size_t)k * 64 + mc) * 8192;
#pragma unroll
    for (int i = 0; i < 4; ++i) {
        int off = i * 2048 + t * 8;
        *(us8*)&hs[off] = *(const us8*)&src[off];
    }
    __syncthreads();
    const int m = t & 63, wq = t >> 6;
    const int base = (m >> 4) * 2048 + ((m >> 3) & 1) * 1024 + (m & 7);
    float si = 0.f, sj = 0.f;
#pragma unroll
    for (int cc = 0; cc < 32; ++cc) {
        int c = wq * 32 + cc;
        float v = bf2f(hs[base + c * 8]);
        si += v * as[c];
        sj += v * ad[c];
    }
    pim[wq][m] = si; pjm[wq][m] = sj;
    __syncthreads();
    if (t < 64) {
        ei[(mc * 64 + t) * KHc + k]        = pim[0][t] + pim[1][t] + pim[2][t] + pim[3][t];
        ejT[(size_t)k * NN + mc * 64 + t]  = pjm[0][t] + pjm[1][t] + pjm[2][t] + pjm[3][t];
    }
}

// ---------------- kernel 3: partial out = P @ H; barrier-free register-P ----------------
// 1024 blocks: block = (k, 32-row tile, m-half). 4 waves each own a private
// 512-m quarter: P generated directly in A-fragment registers (lane l holds
// P[row=l&31][k-elems (l>>5)*8+j]) -> MFMA straight from regs. No barriers in
// the loop; sequential LDS reduce of the 4 wave-partials at the end.
__global__ __launch_bounds__(256, 3) void out_mfma_kernel(const unsigned* __restrict__ bits,
                                                          const float* __restrict__ ei,
                                                          const float* __restrict__ ejT,
                                                          const unsigned short* __restrict__ hB,
                                                          float* __restrict__ pacc,
                                                          float* __restrict__ psum) {
    __shared__ unsigned bitsL[4][544];      // per-wave bits slice, rows padded *17
    __shared__ float ejL[4][512];           // per-wave ej slice
    __shared__ float red[4096];             // sequential cross-wave reduce (16 KB)
    __shared__ float sred[4][32];           // per-wave row sums
    const int bid = blockIdx.x;
    const int nb  = (bid & 7) * 128 + (bid >> 3);   // bijective XCD chunking
    const int k   = nb >> 8;
    const int rt  = (nb & 255) >> 1;
    const int hf  = nb & 1;
    const int n0  = rt * 32;
    const int t = threadIdx.x, lane = t & 63, w = t >> 6;
    const int row = lane & 31, kh = lane >> 5;
    const int mq  = hf * 2048 + w * 512;            // wave's private m range
    // stage bits (wave-private; no barrier needed)
    {
        int r = lane >> 1, cb = (lane & 1) * 8;
        const unsigned* src = &bits[(size_t)(n0 + r) * 128 + (mq >> 5) + cb];
        unsigned* dst = &bitsL[w][r * 17 + cb];
#pragma unroll
        for (int c = 0; c < 8; ++c) dst[c] = src[c];
    }
    // stage ej (wave-private)
    {
        const float* src = &ejT[(size_t)k * NN + mq + lane * 8];
        *(f4*)&ejL[w][lane * 8]     = *(const f4*)src;
        *(f4*)&ejL[w][lane * 8 + 4] = *(const f4*)(src + 4);
    }
    const float eiv = ei[(n0 + row) * KHc + k];
    const char* hbase = (const char*)hB + (size_t)k * 1048576 + (size_t)(mq >> 6) * 16384
                        + kh * 2048 + row * 16;
    bfrag ones;
#pragma unroll
    for (int j = 0; j < 8; ++j) ones[j] = (short)0x3F80;   // bf16 1.0
    f16v acc0 = {}, acc1 = {}, acc2 = {}, acc3 = {}, accs = {};

    for (int it = 0; it < 8; ++it) {
        const char* hc = hbase + (size_t)it * 16384;
        unsigned bw0 = bitsL[w][row * 17 + it * 2];
        unsigned bw1 = bitsL[w][row * 17 + it * 2 + 1];
#pragma unroll
        for (int ks = 0; ks < 4; ++ks) {
            us8 hg0 = *(const us8*)(hc + ks * 4096);
            us8 hg1 = *(const us8*)(hc + ks * 4096 + 512);
            us8 hg2 = *(const us8*)(hc + ks * 4096 + 1024);
            us8 hg3 = *(const us8*)(hc + ks * 4096 + 1536);
            f4 ej0 = *(const f4*)&ejL[w][it * 64 + ks * 16 + kh * 8];
            f4 ej1 = *(const f4*)&ejL[w][it * 64 + ks * 16 + kh * 8 + 4];
            unsigned bw = ((ks & 2) ? bw1 : bw0) >> ((ks & 1) * 16 + kh * 8);
            float p[8];
#pragma unroll
            for (int j = 0; j < 8; ++j) {
                float sc = eiv + (j < 4 ? ej0[j] : ej1[j - 4]);
                sc = fmaxf(sc, ALPHA * sc);
                float pp = exp2f(sc);
                p[j] = ((bw >> j) & 1) ? pp : 0.f;
            }
            union { unsigned u[4]; bfrag s; } pk;
#pragma unroll
            for (int j = 0; j < 4; ++j) {
                float2 fp; fp.x = p[2 * j]; fp.y = p[2 * j + 1];
                __hip_bfloat162 b2 = __float22bfloat162_rn(fp);
                pk.u[j] = *reinterpret_cast<unsigned*>(&b2);
            }
            acc0 = __builtin_amdgcn_mfma_f32_32x32x16_bf16(pk.s, us2bf(hg0), acc0, 0, 0, 0);
            acc1 = __builtin_amdgcn_mfma_f32_32x32x16_bf16(pk.s, us2bf(hg1), acc1, 0, 0, 0);
            acc2 = __builtin_amdgcn_mfma_f32_32x32x16_bf16(pk.s, us2bf(hg2), acc2, 0, 0, 0);
            acc3 = __builtin_amdgcn_mfma_f32_32x32x16_bf16(pk.s, us2bf(hg3), acc3, 0, 0, 0);
            accs = __builtin_amdgcn_mfma_f32_32x32x16_bf16(pk.s, ones, accs, 0, 0, 0);
        }
    }
    // publish per-wave row sums
    if (row == 0) {   // lanes 0 and 32
#pragma unroll
        for (int reg = 0; reg < 16; ++reg) {
            int r = (reg & 3) + 8 * (reg >> 2) + 4 * kh;
            sred[w][r] = accs[reg];
        }
    }
    __syncthreads();
    if (t < 32) psum[(size_t)nb * 32 + t] =
        (sred[0][t] + sred[1][t]) + (sred[2][t] + sred[3][t]);
    // sequential reduce of acc partials: w1 -> w0, then w2, then w3
#pragma unroll
    for (int src = 1; src < 4; ++src) {
        if (w == src) {
#pragma unroll
            for (int cg = 0; cg < 4; ++cg) {
                const f16v& av = (cg == 0) ? acc0 : (cg == 1) ? acc1 : (cg == 2) ? acc2 : acc3;
#pragma unroll
                for (int reg = 0; reg < 16; ++reg) {
                    int r = (reg & 3) + 8 * (reg >> 2) + 4 * kh;
                    red[r * 128 + cg * 32 + row] = av[reg];
                }
            }
        }
        __syncthreads();
        if (w == 0) {
#pragma unroll
            for (int cg = 0; cg < 4; ++cg) {
                f16v& av = (cg == 0) ? acc0 : (cg == 1) ? acc1 : (cg == 2) ? acc2 : acc3;
#pragma unroll
                for (int reg = 0; reg < 16; ++reg) {
                    int r = (reg & 3) + 8 * (reg >> 2) + 4 * kh;
                    av[reg] += red[r * 128 + cg * 32 + row];
                }
            }
        }
        __syncthreads();
    }
    if (w == 0) {
        float* pa = &pacc[(size_t)nb * 4096];
#pragma unroll
        for (int cg = 0; cg < 4; ++cg) {
            const f16v& av = (cg == 0) ? acc0 : (cg == 1) ? acc1 : (cg == 2) ? acc2 : acc3;
#pragma unroll
            for (int reg = 0; reg < 16; ++reg) {
                int r = (reg & 3) + 8 * (reg >> 2) + 4 * kh;
                pa[r * 128 + cg * 32 + row] = av[reg];
            }
        }
    }
}

// ---------------- kernel 4: combine halves, scale by 1/denominator ----------------
__global__ __launch_bounds__(256) void combine_kernel(const float* __restrict__ pacc,
                                                      const float* __restrict__ psum,
                                                      float* __restrict__ out) {
    const int b = blockIdx.x;            // 512: k*128 + rt
    const int k = b >> 7, rt = b & 127;
    const int t = threadIdx.x;
    const int row = t >> 3, cb = (t & 7) * 16;
    const float* a0 = &pacc[(size_t)(b * 2) * 4096 + row * 128 + cb];
    const float* a1 = a0 + 4096;
    float s = psum[(size_t)(b * 2) * 32 + row] + psum[(size_t)(b * 2 + 1) * 32 + row];
    float rinv = 1.0f / s;
    float* o = &out[(size_t)(rt * 32 + row) * KFc + k * FOUTc + cb];
#pragma unroll
    for (int c4 = 0; c4 < 4; ++c4) {
        f4 v0 = *(const f4*)(a0 + c4 * 4);
        f4 v1 = *(const f4*)(a1 + c4 * 4);
        f4 v;
#pragma unroll
        for (int j = 0; j < 4; ++j) v[j] = (v0[j] + v1[j]) * rinv;
        *(f4*)(o + c4 * 4) = v;
    }
}

extern "C" void kernel_launch(void* const* d_in, const int* in_sizes, int n_in,
                              void* d_out, int out_size, void* d_ws, size_t ws_size,
                              hipStream_t stream) {
    const float* x   = (const float*)d_in[0];
    const int*   adj = (const int*)d_in[1];
    const float* W   = (const float*)d_in[2];
    const float* a   = (const float*)d_in[3];
    float* out = (float*)d_out;
    char* ws = (char*)d_ws;

    // layout (~23.4 MB): pacc aliases xb (dead after gemmh_bits)
    unsigned short* hB   = (unsigned short*)ws;                  // 0..4 MB
    unsigned short* xb   = (unsigned short*)(ws + (4u << 20));   // 4..8 MB (dead after gemmh)
    float*          pacc = (float*)(ws + (4u << 20));            // 4..20 MB
    unsigned short* WbT  = (unsigned short*)(ws + (20u << 20));  // 20..20.5 MB
    unsigned*       bits = (unsigned*)(ws + (21u << 20));        // 21..23 MB
    float*          ei   = (float*)(ws + (23u << 20));           // 64 KB
    float*          ejT  = ei + (size_t)NN * KHc;                // 64 KB
    float*          psum = ejT + (size_t)NN * KHc;               // 128 KB

    prep_kernel<<<1088, 256, 0, stream>>>(x, W, xb, WbT);
    gemmh_bits_kernel<<<1536, 256, 0, stream>>>(xb, WbT, adj, hB, bits);
    e2_kernel<<<256, 256, 0, stream>>>(hB, a, ei, ejT);
    out_mfma_kernel<<<1024, 256, 0, stream>>>(bits, ei, ejT, hB, pacc, psum);
    combine_kernel<<<512, 256, 0, stream>>>(pacc, psum, out);
}